// Round 7
// baseline (488.698 us; speedup 1.0000x reference)
//
#include <hip/hip_runtime.h>

typedef unsigned short u16;
typedef u16   u16x8  __attribute__((ext_vector_type(8)));
typedef u16   u16x4  __attribute__((ext_vector_type(4)));
typedef u16   u16x2  __attribute__((ext_vector_type(2)));
typedef short short8v __attribute__((ext_vector_type(8)));
typedef float f32x16  __attribute__((ext_vector_type(16)));

__device__ __forceinline__ u16 f2bf(float f) {
    unsigned u = __float_as_uint(f);
    unsigned r = (u + 0x7fffu + ((u >> 16) & 1u)) >> 16;   // round-to-nearest-even
    return (u16)r;
}
__device__ __forceinline__ float bf2f(u16 h) {
    return __uint_as_float(((unsigned)h) << 16);
}

// ---------------------------------------------------------------------------
// CSR build: count -> scan (+dinv) -> fill.  csr entry = src only (4B);
// coef = dinv[src]*dinv[dst] is recomputed at aggregation time (dinv is
// L2-resident).  4 edges/thread for atomic/scatter ILP.
// ---------------------------------------------------------------------------
__global__ __launch_bounds__(256) void count_kernel(const int* __restrict__ ei, int E,
                                                    int* __restrict__ cnt) {
    int base = blockIdx.x * 1024 + threadIdx.x;
#pragma unroll
    for (int j = 0; j < 4; j++) {
        int e = base + j * 256;
        if (e < E) {
            int d = __builtin_nontemporal_load(ei + E + e);
            atomicAdd(&cnt[d], 1);
        }
    }
}

__global__ __launch_bounds__(256) void scan1_kernel(const int* __restrict__ cnt,
                                                    int* __restrict__ row_start,
                                                    int* __restrict__ bsum,
                                                    float* __restrict__ dinv, int n) {
    __shared__ int sh[256];
    int t = threadIdx.x;
    int base = blockIdx.x * 1024 + t * 4;
    int v0 = 0, v1 = 0, v2 = 0, v3 = 0;
    if (base + 0 < n) { v0 = cnt[base + 0]; dinv[base + 0] = rsqrtf((float)(v0 + 1)); }
    if (base + 1 < n) { v1 = cnt[base + 1]; dinv[base + 1] = rsqrtf((float)(v1 + 1)); }
    if (base + 2 < n) { v2 = cnt[base + 2]; dinv[base + 2] = rsqrtf((float)(v2 + 1)); }
    if (base + 3 < n) { v3 = cnt[base + 3]; dinv[base + 3] = rsqrtf((float)(v3 + 1)); }
    int s = v0 + v1 + v2 + v3;
    sh[t] = s;
    __syncthreads();
    for (int off = 1; off < 256; off <<= 1) {
        int add = (t >= off) ? sh[t - off] : 0;
        __syncthreads();
        sh[t] += add;
        __syncthreads();
    }
    int excl = sh[t] - s;
    if (t == 255) bsum[blockIdx.x] = sh[255];
    int p = excl;
    if (base + 0 < n) row_start[base + 0] = p; p += v0;
    if (base + 1 < n) row_start[base + 1] = p; p += v1;
    if (base + 2 < n) row_start[base + 2] = p; p += v2;
    if (base + 3 < n) row_start[base + 3] = p;
}

// parallel scan of block sums (nb <= 256: n=170000 -> nb=167)
__global__ __launch_bounds__(256) void scan2_kernel(const int* __restrict__ bsum,
                                                    int* __restrict__ boff,
                                                    int* __restrict__ row_start, int nb, int n) {
    __shared__ int sh[256];
    int t = threadIdx.x;
    int v = (t < nb) ? bsum[t] : 0;
    sh[t] = v;
    __syncthreads();
    for (int off = 1; off < 256; off <<= 1) {
        int add = (t >= off) ? sh[t - off] : 0;
        __syncthreads();
        sh[t] += add;
        __syncthreads();
    }
    if (t < nb) boff[t] = sh[t] - v;
    if (t == 255) row_start[n] = sh[255];
}

__global__ __launch_bounds__(256) void scan3_kernel(int* __restrict__ row_start,
                                                    int* __restrict__ cursor,
                                                    const int* __restrict__ boff, int n) {
    int t = threadIdx.x;
    int base = blockIdx.x * 1024 + t * 4;
    int off = boff[blockIdx.x];
#pragma unroll
    for (int i = 0; i < 4; i++) {
        int idx = base + i;
        if (idx < n) {
            int v = row_start[idx] + off;
            row_start[idx] = v;
            cursor[idx] = v;
        }
    }
}

__global__ __launch_bounds__(256) void fill_kernel(const int* __restrict__ ei, int E,
                                                   int* __restrict__ cursor,
                                                   int* __restrict__ csr_src) {
    int base = blockIdx.x * 1024 + threadIdx.x;
#pragma unroll
    for (int j = 0; j < 4; j++) {
        int e = base + j * 256;
        if (e < E) {
            int s = __builtin_nontemporal_load(ei + e);
            int d = __builtin_nontemporal_load(ei + E + e);
            int pos = atomicAdd(&cursor[d], 1);
            csr_src[pos] = s;
        }
    }
}

// ---------------------------------------------------------------------------
// All weights -> bf16 [col][k] transposed, one launch.
// W1,W2: [128][128] -> 128x128. W3: [128][40] -> padded [64][128] (cols 40+ = 0)
// ---------------------------------------------------------------------------
__global__ void wconv_all(const float* __restrict__ W1, const float* __restrict__ W2,
                          const float* __restrict__ W3,
                          u16* __restrict__ WT1, u16* __restrict__ WT2,
                          u16* __restrict__ WT3) {
    int i = blockIdx.x * 256 + threadIdx.x;   // 0..40959
    if (i < 32768) {
        const float* W = (i < 16384) ? W1 : W2;
        u16* WT = (i < 16384) ? WT1 : WT2;
        int j = i & 16383;
        int k = j >> 7, col = j & 127;
        WT[col * 128 + k] = f2bf(W[j]);
    } else {
        int j = i - 32768;                    // 0..8191
        int col = j >> 7, k = j & 127;        // col 0..63
        WT3[j] = (col < 40) ? f2bf(W3[k * 40 + col]) : (u16)0;
    }
}

// ---------------------------------------------------------------------------
// out[n x 128](bf16) = A[n x 128] @ W[128 x 128] via bf16 MFMA, fp32 accum.
// A fp32 (layer 1) or bf16 (layer 2). LDS: buf[row*128 + (k ^ ((row&7)<<3))]
// ---------------------------------------------------------------------------
template <bool ABF>
__global__ __launch_bounds__(256) void gemm128_mfma(const void* __restrict__ Ap,
                                                    const u16* __restrict__ WT,
                                                    u16* __restrict__ out, int n) {
    __shared__ u16 As[128 * 128];
    __shared__ u16 Bs[128 * 128];
    const int t = threadIdx.x;
    const int r0 = blockIdx.x * 128;

#pragma unroll
    for (int j = 0; j < 8; j++) {
        int f = t + j * 256;
        int col = f >> 4;
        int k0 = (f & 15) * 8;
        u16x8 v = *(const u16x8*)(WT + col * 128 + k0);
        *(u16x8*)&Bs[col * 128 + (k0 ^ ((col & 7) << 3))] = v;
    }
    if (ABF) {
        const u16* A = (const u16*)Ap;
#pragma unroll
        for (int j = 0; j < 8; j++) {
            int f = t + j * 256;
            int row = f >> 4;
            int k0 = (f & 15) * 8;
            u16x8 v = {0, 0, 0, 0, 0, 0, 0, 0};
            if (r0 + row < n) v = *(const u16x8*)(A + (size_t)(r0 + row) * 128 + k0);
            *(u16x8*)&As[row * 128 + (k0 ^ ((row & 7) << 3))] = v;
        }
    } else {
        const float* A = (const float*)Ap;
#pragma unroll
        for (int j = 0; j < 16; j++) {
            int f = t + j * 256;
            int row = f >> 5;
            int k0 = (f & 31) * 4;
            float4 v = make_float4(0.f, 0.f, 0.f, 0.f);
            if (r0 + row < n) v = *(const float4*)(A + (size_t)(r0 + row) * 128 + k0);
            u16x4 b;
            b[0] = f2bf(v.x); b[1] = f2bf(v.y); b[2] = f2bf(v.z); b[3] = f2bf(v.w);
            *(u16x4*)&As[row * 128 + (k0 ^ ((row & 7) << 3))] = b;
        }
    }
    __syncthreads();

    const int w = t >> 6, lane = t & 63;
    const int wr = (w >> 1) * 64;
    const int wc = (w & 1) * 64;
    const int lr = lane & 31;
    const int kj = (lane >> 5) * 8;
    const int swz = (lr & 7) << 3;

    f32x16 acc00, acc01, acc10, acc11;
#pragma unroll
    for (int i = 0; i < 16; i++) { acc00[i] = 0.f; acc01[i] = 0.f; acc10[i] = 0.f; acc11[i] = 0.f; }

#pragma unroll
    for (int ks = 0; ks < 8; ks++) {
        int ko = (ks * 16 + kj) ^ swz;
        short8v a0 = *(const short8v*)&As[(wr + lr) * 128 + ko];
        short8v a1 = *(const short8v*)&As[(wr + 32 + lr) * 128 + ko];
        short8v b0 = *(const short8v*)&Bs[(wc + lr) * 128 + ko];
        short8v b1 = *(const short8v*)&Bs[(wc + 32 + lr) * 128 + ko];
        acc00 = __builtin_amdgcn_mfma_f32_32x32x16_bf16(a0, b0, acc00, 0, 0, 0);
        acc01 = __builtin_amdgcn_mfma_f32_32x32x16_bf16(a0, b1, acc01, 0, 0, 0);
        acc10 = __builtin_amdgcn_mfma_f32_32x32x16_bf16(a1, b0, acc10, 0, 0, 0);
        acc11 = __builtin_amdgcn_mfma_f32_32x32x16_bf16(a1, b1, acc11, 0, 0, 0);
    }

    const int rb = (lane >> 5) * 4;
#pragma unroll
    for (int r = 0; r < 16; r++) {
        int rr = (r & 3) + 8 * (r >> 2) + rb;
        int row0 = r0 + wr + rr;
        int row1 = r0 + wr + 32 + rr;
        if (row0 < n) {
            out[(size_t)row0 * 128 + wc + lr]      = f2bf(acc00[r]);
            out[(size_t)row0 * 128 + wc + 32 + lr] = f2bf(acc01[r]);
        }
        if (row1 < n) {
            out[(size_t)row1 * 128 + wc + lr]      = f2bf(acc10[r]);
            out[(size_t)row1 * 128 + wc + 32 + lr] = f2bf(acc11[r]);
        }
    }
}

// ---------------------------------------------------------------------------
// g3[n x 40](bf16) = A[n x 128](bf16) @ W3pad[128 x 64](bf16) via MFMA.
// ---------------------------------------------------------------------------
__global__ __launch_bounds__(256) void gemm40_mfma(const u16* __restrict__ A,
                                                   const u16* __restrict__ WT3,
                                                   u16* __restrict__ out, int n) {
    __shared__ u16 As[128 * 128];
    __shared__ u16 Bs[64 * 128];
    const int t = threadIdx.x;
    const int r0 = blockIdx.x * 128;

#pragma unroll
    for (int j = 0; j < 4; j++) {
        int f = t + j * 256;
        int col = f >> 4;
        int k0 = (f & 15) * 8;
        u16x8 v = *(const u16x8*)(WT3 + col * 128 + k0);
        *(u16x8*)&Bs[col * 128 + (k0 ^ ((col & 7) << 3))] = v;
    }
#pragma unroll
    for (int j = 0; j < 8; j++) {
        int f = t + j * 256;
        int row = f >> 4;
        int k0 = (f & 15) * 8;
        u16x8 v = {0, 0, 0, 0, 0, 0, 0, 0};
        if (r0 + row < n) v = *(const u16x8*)(A + (size_t)(r0 + row) * 128 + k0);
        *(u16x8*)&As[row * 128 + (k0 ^ ((row & 7) << 3))] = v;
    }
    __syncthreads();

    const int w = t >> 6, lane = t & 63;
    const int wr = w * 32;
    const int lr = lane & 31;
    const int kj = (lane >> 5) * 8;
    const int swz = (lr & 7) << 3;

    f32x16 acc0, acc1;
#pragma unroll
    for (int i = 0; i < 16; i++) { acc0[i] = 0.f; acc1[i] = 0.f; }

#pragma unroll
    for (int ks = 0; ks < 8; ks++) {
        int ko = (ks * 16 + kj) ^ swz;
        short8v a  = *(const short8v*)&As[(wr + lr) * 128 + ko];
        short8v b0 = *(const short8v*)&Bs[lr * 128 + ko];
        short8v b1 = *(const short8v*)&Bs[(32 + lr) * 128 + ko];
        acc0 = __builtin_amdgcn_mfma_f32_32x32x16_bf16(a, b0, acc0, 0, 0, 0);
        acc1 = __builtin_amdgcn_mfma_f32_32x32x16_bf16(a, b1, acc1, 0, 0, 0);
    }

    const int rb = (lane >> 5) * 4;
#pragma unroll
    for (int r = 0; r < 16; r++) {
        int rr = (r & 3) + 8 * (r >> 2) + rb;
        int row = r0 + wr + rr;
        if (row < n) {
            out[(size_t)row * 40 + lr] = f2bf(acc0[r]);
            if (lr < 8) out[(size_t)row * 40 + 32 + lr] = f2bf(acc1[r]);
        }
    }
}

// ---------------------------------------------------------------------------
// pull aggregation, 128 bf16 features: 16 nodes / 256-thr block,
// 16 lanes/node x 8 bf16 (16B loads), 4-deep unroll, coef from dinv.
// ---------------------------------------------------------------------------
__global__ __launch_bounds__(256) void agg128_bf16(const u16* __restrict__ hw,
                                                   const float* __restrict__ dinv,
                                                   const int* __restrict__ row_start,
                                                   const int* __restrict__ csr_src,
                                                   const float* __restrict__ bias,
                                                   u16* __restrict__ out, int n,
                                                   int do_relu) {
    int t = threadIdx.x;
    int node = blockIdx.x * 16 + (t >> 4);
    int f = t & 15;
    if (node >= n) return;
    const u16x8* hw8 = (const u16x8*)hw;
    float di = dinv[node];
    float s2 = di * di;
    u16x8 v = hw8[(size_t)node * 16 + f];
    float acc[8];
#pragma unroll
    for (int j = 0; j < 8; j++) acc[j] = bf2f(v[j]) * s2;

    int e0 = row_start[node], e1 = row_start[node + 1];
    int e = e0;
    for (; e + 3 < e1; e += 4) {
        int s0v = csr_src[e], s1v = csr_src[e + 1], s2v = csr_src[e + 2], s3v = csr_src[e + 3];
        float c0 = dinv[s0v] * di, c1 = dinv[s1v] * di;
        float c2 = dinv[s2v] * di, c3 = dinv[s3v] * di;
        u16x8 u0 = hw8[(size_t)s0v * 16 + f];
        u16x8 u1 = hw8[(size_t)s1v * 16 + f];
        u16x8 u2 = hw8[(size_t)s2v * 16 + f];
        u16x8 u3 = hw8[(size_t)s3v * 16 + f];
#pragma unroll
        for (int j = 0; j < 8; j++) acc[j] = fmaf(c0, bf2f(u0[j]), acc[j]);
#pragma unroll
        for (int j = 0; j < 8; j++) acc[j] = fmaf(c1, bf2f(u1[j]), acc[j]);
#pragma unroll
        for (int j = 0; j < 8; j++) acc[j] = fmaf(c2, bf2f(u2[j]), acc[j]);
#pragma unroll
        for (int j = 0; j < 8; j++) acc[j] = fmaf(c3, bf2f(u3[j]), acc[j]);
    }
    for (; e < e1; e++) {
        int sv = csr_src[e];
        float c0 = dinv[sv] * di;
        u16x8 u0 = hw8[(size_t)sv * 16 + f];
#pragma unroll
        for (int j = 0; j < 8; j++) acc[j] = fmaf(c0, bf2f(u0[j]), acc[j]);
    }

    const float4* b4 = (const float4*)bias;
    float4 ba = b4[f * 2], bb = b4[f * 2 + 1];
    float bv[8] = {ba.x, ba.y, ba.z, ba.w, bb.x, bb.y, bb.z, bb.w};
    u16x8 o;
#pragma unroll
    for (int j = 0; j < 8; j++) {
        float r = acc[j] + bv[j];
        if (do_relu) r = fmaxf(r, 0.f);
        o[j] = f2bf(r);
    }
    *((u16x8*)out + (size_t)node * 16 + f) = o;
}

// ---------------------------------------------------------------------------
// final aggregation, 40 bf16 features -> fp32 out.
// Block 320: 16 nodes, 20 lanes/node, 2 features (u16x2 = 4B) per lane.
// ---------------------------------------------------------------------------
__global__ __launch_bounds__(320) void agg40_bf16(const u16* __restrict__ g3,
                                                  const float* __restrict__ dinv,
                                                  const int* __restrict__ row_start,
                                                  const int* __restrict__ csr_src,
                                                  const float* __restrict__ bias,
                                                  float* __restrict__ out, int n) {
    int t = threadIdx.x;
    int node = blockIdx.x * 16 + t / 20;
    int fq = t % 20;                    // features 2fq, 2fq+1
    if (node >= n) return;
    float di = dinv[node];
    float s2 = di * di;
    u16x2 v = *(const u16x2*)(g3 + (size_t)node * 40 + fq * 2);
    float a0 = bf2f(v[0]) * s2;
    float a1 = bf2f(v[1]) * s2;

    int e0 = row_start[node], e1 = row_start[node + 1];
    int e = e0;
    for (; e + 3 < e1; e += 4) {
        int s0v = csr_src[e], s1v = csr_src[e + 1], s2v = csr_src[e + 2], s3v = csr_src[e + 3];
        float c0 = dinv[s0v] * di, c1 = dinv[s1v] * di;
        float c2 = dinv[s2v] * di, c3 = dinv[s3v] * di;
        u16x2 u0 = *(const u16x2*)(g3 + (size_t)s0v * 40 + fq * 2);
        u16x2 u1 = *(const u16x2*)(g3 + (size_t)s1v * 40 + fq * 2);
        u16x2 u2 = *(const u16x2*)(g3 + (size_t)s2v * 40 + fq * 2);
        u16x2 u3 = *(const u16x2*)(g3 + (size_t)s3v * 40 + fq * 2);
        a0 = fmaf(c0, bf2f(u0[0]), a0); a1 = fmaf(c0, bf2f(u0[1]), a1);
        a0 = fmaf(c1, bf2f(u1[0]), a0); a1 = fmaf(c1, bf2f(u1[1]), a1);
        a0 = fmaf(c2, bf2f(u2[0]), a0); a1 = fmaf(c2, bf2f(u2[1]), a1);
        a0 = fmaf(c3, bf2f(u3[0]), a0); a1 = fmaf(c3, bf2f(u3[1]), a1);
    }
    for (; e < e1; e++) {
        int sv = csr_src[e];
        float c0 = dinv[sv] * di;
        u16x2 u0 = *(const u16x2*)(g3 + (size_t)sv * 40 + fq * 2);
        a0 = fmaf(c0, bf2f(u0[0]), a0); a1 = fmaf(c0, bf2f(u0[1]), a1);
    }

    float2 b2v = *(const float2*)(bias + fq * 2);
    float2 o = make_float2(a0 + b2v.x, a1 + b2v.y);
    *(float2*)(out + (size_t)node * 40 + fq * 2) = o;
}

extern "C" void kernel_launch(void* const* d_in, const int* in_sizes, int n_in,
                              void* d_out, int out_size, void* d_ws, size_t ws_size,
                              hipStream_t stream) {
    const float* x  = (const float*)d_in[0];
    const int*   ei = (const int*)d_in[1];
    const float* W1 = (const float*)d_in[2];
    const float* b1 = (const float*)d_in[3];
    const float* W2 = (const float*)d_in[4];
    const float* b2 = (const float*)d_in[5];
    const float* W3 = (const float*)d_in[6];
    const float* b3 = (const float*)d_in[7];
    float* out = (float*)d_out;

    const int n = in_sizes[0] / 128;   // 170000
    const int E = in_sizes[1] / 2;     // 1200000

    // workspace carve (256B aligned)
    char* p = (char*)d_ws;
    auto alloc = [&](size_t bytes) { void* r = (void*)p; p += (bytes + 255) & ~(size_t)255; return r; };
    int*   cnt       = (int*)alloc((size_t)n * 4);
    int*   row_start = (int*)alloc((size_t)(n + 1) * 4);
    int*   cursor    = (int*)alloc((size_t)n * 4);
    int*   bsum      = (int*)alloc(1024 * 4);
    int*   boff      = (int*)alloc(1024 * 4);
    float* dinv      = (float*)alloc((size_t)n * 4);
    int*   csr_src   = (int*)alloc((size_t)E * 4);
    u16*   bufG      = (u16*)alloc((size_t)n * 128 * 2);   // gemm outputs (bf16)
    u16*   bufH      = (u16*)alloc((size_t)n * 128 * 2);   // agg outputs (bf16)
    u16*   g3b       = (u16*)alloc((size_t)n * 40 * 2);    // layer-3 gemm out (bf16)
    u16*   wt1       = (u16*)alloc(16384 * 2);
    u16*   wt2       = (u16*)alloc(16384 * 2);
    u16*   wt3       = (u16*)alloc(8192 * 2);              // [64][128], cols 40+ zero

    // --- weight convert (one launch: W1, W2, W3pad) ---
    wconv_all<<<160, 256, 0, stream>>>(W1, W2, W3, wt1, wt2, wt3);

    // --- CSR build ---
    hipMemsetAsync(cnt, 0, (size_t)n * 4, stream);
    count_kernel<<<(E + 1023) / 1024, 256, 0, stream>>>(ei, E, cnt);
    int nb = (n + 1023) / 1024;
    scan1_kernel<<<nb, 256, 0, stream>>>(cnt, row_start, bsum, dinv, n);
    scan2_kernel<<<1, 256, 0, stream>>>(bsum, boff, row_start, nb, n);
    scan3_kernel<<<nb, 256, 0, stream>>>(row_start, cursor, boff, n);
    fill_kernel<<<(E + 1023) / 1024, 256, 0, stream>>>(ei, E, cursor, csr_src);

    const int gblk = (n + 127) / 128;

    // --- layer 1 (A fp32) ---
    gemm128_mfma<false><<<gblk, 256, 0, stream>>>(x, wt1, bufG, n);
    agg128_bf16<<<(n + 15) / 16, 256, 0, stream>>>(bufG, dinv, row_start, csr_src, b1, bufH, n, 1);
    // --- layer 2 (A bf16) ---
    gemm128_mfma<true><<<gblk, 256, 0, stream>>>(bufH, wt2, bufG, n);
    agg128_bf16<<<(n + 15) / 16, 256, 0, stream>>>(bufG, dinv, row_start, csr_src, b2, bufH, n, 1);
    // --- layer 3 (W first: A(hW3) == (Ah)W3, aggregate only 40 features) ---
    gemm40_mfma<<<gblk, 256, 0, stream>>>(bufH, wt3, g3b, n);
    agg40_bf16<<<(n + 15) / 16, 320, 0, stream>>>(g3b, dinv, row_start, csr_src, b3, out, n);
}

// Round 8
// 418.623 us; speedup vs baseline: 1.1674x; 1.1674x over previous
//
#include <hip/hip_runtime.h>

typedef unsigned short u16;
typedef u16   u16x8  __attribute__((ext_vector_type(8)));
typedef u16   u16x4  __attribute__((ext_vector_type(4)));
typedef u16   u16x2  __attribute__((ext_vector_type(2)));
typedef short short8v __attribute__((ext_vector_type(8)));
typedef float f32x16  __attribute__((ext_vector_type(16)));

__device__ __forceinline__ u16 f2bf(float f) {
    unsigned u = __float_as_uint(f);
    unsigned r = (u + 0x7fffu + ((u >> 16) & 1u)) >> 16;   // round-to-nearest-even
    return (u16)r;
}
__device__ __forceinline__ float bf2f(u16 h) {
    return __uint_as_float(((unsigned)h) << 16);
}

// ---------------------------------------------------------------------------
// Bucketed CSR build. Buckets of 512 nodes (dst>>9). No per-node global
// atomics anywhere; scatter writes are bucket-local so L2 lines merge.
//   histA: per-bucket edge counts (LDS-aggregated)
//   scanA: bucket region offsets bstart[], bcur[] (csr and ebuf share offsets)
//   bucket_scatter: edges -> ebuf grouped by bucket (block-aggregated appends)
//   fine_fill: per-bucket LDS counting sort -> row_start, dinv, csr_src
// ---------------------------------------------------------------------------
__global__ __launch_bounds__(256) void histA_kernel(const int* __restrict__ ei, int E,
                                                    int* __restrict__ bhist) {
    __shared__ int h[512];
    int t = threadIdx.x;
    h[t] = 0; h[t + 256] = 0;
    __syncthreads();
    int base = blockIdx.x * 4096 + t;
#pragma unroll
    for (int j = 0; j < 16; j++) {
        int e = base + j * 256;
        if (e < E) {
            int d = __builtin_nontemporal_load(ei + E + e);
            atomicAdd(&h[d >> 9], 1);
        }
    }
    __syncthreads();
    if (h[t])       atomicAdd(&bhist[t], h[t]);
    if (h[t + 256]) atomicAdd(&bhist[t + 256], h[t + 256]);
}

__global__ __launch_bounds__(256) void scanA_kernel(const int* __restrict__ bhist,
                                                    int* __restrict__ bstart,
                                                    int* __restrict__ bcur, int nb) {
    __shared__ int hh[512];
    __shared__ int ps[256];
    int t = threadIdx.x;
    hh[t]       = (t < nb) ? bhist[t] : 0;
    hh[t + 256] = (t + 256 < nb) ? bhist[t + 256] : 0;
    __syncthreads();
    int a0 = hh[2 * t], a1 = hh[2 * t + 1];
    int s = a0 + a1;
    ps[t] = s;
    __syncthreads();
    for (int off = 1; off < 256; off <<= 1) {
        int add = (t >= off) ? ps[t - off] : 0;
        __syncthreads();
        ps[t] += add;
        __syncthreads();
    }
    int ex = ps[t] - s;
    bstart[2 * t] = ex;         bcur[2 * t] = ex;
    bstart[2 * t + 1] = ex + a0; bcur[2 * t + 1] = ex + a0;
    if (t == 255) bstart[512] = ps[255];
}

__global__ __launch_bounds__(256) void bucket_scatter(const int* __restrict__ ei, int E,
                                                      int* __restrict__ bcur,
                                                      int2* __restrict__ ebuf) {
    __shared__ int h[512];
    __shared__ int gb[512];
    int t = threadIdx.x;
    h[t] = 0; h[t + 256] = 0;
    __syncthreads();
    int base = blockIdx.x * 4096 + t;
    int ss[16], dd[16], lr[16];
#pragma unroll
    for (int j = 0; j < 16; j++) {
        int e = base + j * 256;
        if (e < E) {
            ss[j] = __builtin_nontemporal_load(ei + e);
            dd[j] = __builtin_nontemporal_load(ei + E + e);
            lr[j] = atomicAdd(&h[dd[j] >> 9], 1);
        } else {
            dd[j] = -1;
        }
    }
    __syncthreads();
    if (h[t])       gb[t] = atomicAdd(&bcur[t], h[t]);
    if (h[t + 256]) gb[t + 256] = atomicAdd(&bcur[t + 256], h[t + 256]);
    __syncthreads();
#pragma unroll
    for (int j = 0; j < 16; j++) {
        if (dd[j] >= 0) {
            int b = dd[j] >> 9;
            ebuf[gb[b] + lr[j]] = make_int2(ss[j], dd[j]);
        }
    }
}

__global__ __launch_bounds__(256) void fine_fill(const int2* __restrict__ ebuf,
                                                 const int* __restrict__ bstart,
                                                 int* __restrict__ row_start,
                                                 float* __restrict__ dinv,
                                                 int* __restrict__ csr_src,
                                                 int n, int nb, int E) {
    __shared__ int h[512];
    __shared__ int cur[512];
    __shared__ int ps[256];
    int b = blockIdx.x;
    int t = threadIdx.x;
    int base = b << 9;
    int range = n - base; if (range > 512) range = 512;
    int bs = bstart[b], be = bstart[b + 1];

    h[t] = 0; h[t + 256] = 0;
    __syncthreads();
    for (int i = bs + t; i < be; i += 256) {
        int2 e = ebuf[i];
        atomicAdd(&h[e.y - base], 1);
    }
    __syncthreads();
    // dinv from raw counts (+1 self loop)
    if (t < range)       dinv[base + t] = rsqrtf((float)(h[t] + 1));
    if (t + 256 < range) dinv[base + t + 256] = rsqrtf((float)(h[t + 256] + 1));
    // 512-wide exclusive scan via 256 pair sums
    int a0 = h[2 * t], a1 = h[2 * t + 1];
    int s = a0 + a1;
    ps[t] = s;
    __syncthreads();
    for (int off = 1; off < 256; off <<= 1) {
        int add = (t >= off) ? ps[t - off] : 0;
        __syncthreads();
        ps[t] += add;
        __syncthreads();
    }
    int ex = ps[t] - s;
    cur[2 * t] = ex;
    cur[2 * t + 1] = ex + a0;
    if (2 * t < range)     row_start[base + 2 * t] = bs + ex;
    if (2 * t + 1 < range) row_start[base + 2 * t + 1] = bs + ex + a0;
    if (b == nb - 1 && t == 0) row_start[n] = E;
    __syncthreads();
    for (int i = bs + t; i < be; i += 256) {
        int2 e = ebuf[i];
        int lp = atomicAdd(&cur[e.y - base], 1);
        csr_src[bs + lp] = e.x;
    }
}

// ---------------------------------------------------------------------------
// All weights -> bf16 [col][k] transposed, one launch.
// W1,W2: [128][128] -> 128x128. W3: [128][40] -> padded [64][128] (cols 40+ = 0)
// ---------------------------------------------------------------------------
__global__ void wconv_all(const float* __restrict__ W1, const float* __restrict__ W2,
                          const float* __restrict__ W3,
                          u16* __restrict__ WT1, u16* __restrict__ WT2,
                          u16* __restrict__ WT3) {
    int i = blockIdx.x * 256 + threadIdx.x;   // 0..40959
    if (i < 32768) {
        const float* W = (i < 16384) ? W1 : W2;
        u16* WT = (i < 16384) ? WT1 : WT2;
        int j = i & 16383;
        int k = j >> 7, col = j & 127;
        WT[col * 128 + k] = f2bf(W[j]);
    } else {
        int j = i - 32768;                    // 0..8191
        int col = j >> 7, k = j & 127;        // col 0..63
        WT3[j] = (col < 40) ? f2bf(W3[k * 40 + col]) : (u16)0;
    }
}

// ---------------------------------------------------------------------------
// out[n x 128](bf16) = A[n x 128] @ W[128 x 128] via bf16 MFMA, fp32 accum.
// A fp32 (layer 1) or bf16 (layer 2). LDS: buf[row*128 + (k ^ ((row&7)<<3))]
// ---------------------------------------------------------------------------
template <bool ABF>
__global__ __launch_bounds__(256) void gemm128_mfma(const void* __restrict__ Ap,
                                                    const u16* __restrict__ WT,
                                                    u16* __restrict__ out, int n) {
    __shared__ u16 As[128 * 128];
    __shared__ u16 Bs[128 * 128];
    const int t = threadIdx.x;
    const int r0 = blockIdx.x * 128;

#pragma unroll
    for (int j = 0; j < 8; j++) {
        int f = t + j * 256;
        int col = f >> 4;
        int k0 = (f & 15) * 8;
        u16x8 v = *(const u16x8*)(WT + col * 128 + k0);
        *(u16x8*)&Bs[col * 128 + (k0 ^ ((col & 7) << 3))] = v;
    }
    if (ABF) {
        const u16* A = (const u16*)Ap;
#pragma unroll
        for (int j = 0; j < 8; j++) {
            int f = t + j * 256;
            int row = f >> 4;
            int k0 = (f & 15) * 8;
            u16x8 v = {0, 0, 0, 0, 0, 0, 0, 0};
            if (r0 + row < n) v = *(const u16x8*)(A + (size_t)(r0 + row) * 128 + k0);
            *(u16x8*)&As[row * 128 + (k0 ^ ((row & 7) << 3))] = v;
        }
    } else {
        const float* A = (const float*)Ap;
#pragma unroll
        for (int j = 0; j < 16; j++) {
            int f = t + j * 256;
            int row = f >> 5;
            int k0 = (f & 31) * 4;
            float4 v = make_float4(0.f, 0.f, 0.f, 0.f);
            if (r0 + row < n) v = *(const float4*)(A + (size_t)(r0 + row) * 128 + k0);
            u16x4 b;
            b[0] = f2bf(v.x); b[1] = f2bf(v.y); b[2] = f2bf(v.z); b[3] = f2bf(v.w);
            *(u16x4*)&As[row * 128 + (k0 ^ ((row & 7) << 3))] = b;
        }
    }
    __syncthreads();

    const int w = t >> 6, lane = t & 63;
    const int wr = (w >> 1) * 64;
    const int wc = (w & 1) * 64;
    const int lr = lane & 31;
    const int kj = (lane >> 5) * 8;
    const int swz = (lr & 7) << 3;

    f32x16 acc00, acc01, acc10, acc11;
#pragma unroll
    for (int i = 0; i < 16; i++) { acc00[i] = 0.f; acc01[i] = 0.f; acc10[i] = 0.f; acc11[i] = 0.f; }

#pragma unroll
    for (int ks = 0; ks < 8; ks++) {
        int ko = (ks * 16 + kj) ^ swz;
        short8v a0 = *(const short8v*)&As[(wr + lr) * 128 + ko];
        short8v a1 = *(const short8v*)&As[(wr + 32 + lr) * 128 + ko];
        short8v b0 = *(const short8v*)&Bs[(wc + lr) * 128 + ko];
        short8v b1 = *(const short8v*)&Bs[(wc + 32 + lr) * 128 + ko];
        acc00 = __builtin_amdgcn_mfma_f32_32x32x16_bf16(a0, b0, acc00, 0, 0, 0);
        acc01 = __builtin_amdgcn_mfma_f32_32x32x16_bf16(a0, b1, acc01, 0, 0, 0);
        acc10 = __builtin_amdgcn_mfma_f32_32x32x16_bf16(a1, b0, acc10, 0, 0, 0);
        acc11 = __builtin_amdgcn_mfma_f32_32x32x16_bf16(a1, b1, acc11, 0, 0, 0);
    }

    const int rb = (lane >> 5) * 4;
#pragma unroll
    for (int r = 0; r < 16; r++) {
        int rr = (r & 3) + 8 * (r >> 2) + rb;
        int row0 = r0 + wr + rr;
        int row1 = r0 + wr + 32 + rr;
        if (row0 < n) {
            out[(size_t)row0 * 128 + wc + lr]      = f2bf(acc00[r]);
            out[(size_t)row0 * 128 + wc + 32 + lr] = f2bf(acc01[r]);
        }
        if (row1 < n) {
            out[(size_t)row1 * 128 + wc + lr]      = f2bf(acc10[r]);
            out[(size_t)row1 * 128 + wc + 32 + lr] = f2bf(acc11[r]);
        }
    }
}

// ---------------------------------------------------------------------------
// g3[n x 40](bf16) = A[n x 128](bf16) @ W3pad[128 x 64](bf16) via MFMA.
// ---------------------------------------------------------------------------
__global__ __launch_bounds__(256) void gemm40_mfma(const u16* __restrict__ A,
                                                   const u16* __restrict__ WT3,
                                                   u16* __restrict__ out, int n) {
    __shared__ u16 As[128 * 128];
    __shared__ u16 Bs[64 * 128];
    const int t = threadIdx.x;
    const int r0 = blockIdx.x * 128;

#pragma unroll
    for (int j = 0; j < 4; j++) {
        int f = t + j * 256;
        int col = f >> 4;
        int k0 = (f & 15) * 8;
        u16x8 v = *(const u16x8*)(WT3 + col * 128 + k0);
        *(u16x8*)&Bs[col * 128 + (k0 ^ ((col & 7) << 3))] = v;
    }
#pragma unroll
    for (int j = 0; j < 8; j++) {
        int f = t + j * 256;
        int row = f >> 4;
        int k0 = (f & 15) * 8;
        u16x8 v = {0, 0, 0, 0, 0, 0, 0, 0};
        if (r0 + row < n) v = *(const u16x8*)(A + (size_t)(r0 + row) * 128 + k0);
        *(u16x8*)&As[row * 128 + (k0 ^ ((row & 7) << 3))] = v;
    }
    __syncthreads();

    const int w = t >> 6, lane = t & 63;
    const int wr = w * 32;
    const int lr = lane & 31;
    const int kj = (lane >> 5) * 8;
    const int swz = (lr & 7) << 3;

    f32x16 acc0, acc1;
#pragma unroll
    for (int i = 0; i < 16; i++) { acc0[i] = 0.f; acc1[i] = 0.f; }

#pragma unroll
    for (int ks = 0; ks < 8; ks++) {
        int ko = (ks * 16 + kj) ^ swz;
        short8v a  = *(const short8v*)&As[(wr + lr) * 128 + ko];
        short8v b0 = *(const short8v*)&Bs[lr * 128 + ko];
        short8v b1 = *(const short8v*)&Bs[(32 + lr) * 128 + ko];
        acc0 = __builtin_amdgcn_mfma_f32_32x32x16_bf16(a, b0, acc0, 0, 0, 0);
        acc1 = __builtin_amdgcn_mfma_f32_32x32x16_bf16(a, b1, acc1, 0, 0, 0);
    }

    const int rb = (lane >> 5) * 4;
#pragma unroll
    for (int r = 0; r < 16; r++) {
        int rr = (r & 3) + 8 * (r >> 2) + rb;
        int row = r0 + wr + rr;
        if (row < n) {
            out[(size_t)row * 40 + lr] = f2bf(acc0[r]);
            if (lr < 8) out[(size_t)row * 40 + 32 + lr] = f2bf(acc1[r]);
        }
    }
}

// ---------------------------------------------------------------------------
// pull aggregation, 128 bf16 features: 16 nodes / 256-thr block,
// 16 lanes/node x 8 bf16 (16B loads), 4-deep unroll, coef from dinv.
// ---------------------------------------------------------------------------
__global__ __launch_bounds__(256) void agg128_bf16(const u16* __restrict__ hw,
                                                   const float* __restrict__ dinv,
                                                   const int* __restrict__ row_start,
                                                   const int* __restrict__ csr_src,
                                                   const float* __restrict__ bias,
                                                   u16* __restrict__ out, int n,
                                                   int do_relu) {
    int t = threadIdx.x;
    int node = blockIdx.x * 16 + (t >> 4);
    int f = t & 15;
    if (node >= n) return;
    const u16x8* hw8 = (const u16x8*)hw;
    float di = dinv[node];
    float s2 = di * di;
    u16x8 v = hw8[(size_t)node * 16 + f];
    float acc[8];
#pragma unroll
    for (int j = 0; j < 8; j++) acc[j] = bf2f(v[j]) * s2;

    int e0 = row_start[node], e1 = row_start[node + 1];
    int e = e0;
    for (; e + 3 < e1; e += 4) {
        int s0v = csr_src[e], s1v = csr_src[e + 1], s2v = csr_src[e + 2], s3v = csr_src[e + 3];
        float c0 = dinv[s0v] * di, c1 = dinv[s1v] * di;
        float c2 = dinv[s2v] * di, c3 = dinv[s3v] * di;
        u16x8 u0 = hw8[(size_t)s0v * 16 + f];
        u16x8 u1 = hw8[(size_t)s1v * 16 + f];
        u16x8 u2 = hw8[(size_t)s2v * 16 + f];
        u16x8 u3 = hw8[(size_t)s3v * 16 + f];
#pragma unroll
        for (int j = 0; j < 8; j++) acc[j] = fmaf(c0, bf2f(u0[j]), acc[j]);
#pragma unroll
        for (int j = 0; j < 8; j++) acc[j] = fmaf(c1, bf2f(u1[j]), acc[j]);
#pragma unroll
        for (int j = 0; j < 8; j++) acc[j] = fmaf(c2, bf2f(u2[j]), acc[j]);
#pragma unroll
        for (int j = 0; j < 8; j++) acc[j] = fmaf(c3, bf2f(u3[j]), acc[j]);
    }
    for (; e < e1; e++) {
        int sv = csr_src[e];
        float c0 = dinv[sv] * di;
        u16x8 u0 = hw8[(size_t)sv * 16 + f];
#pragma unroll
        for (int j = 0; j < 8; j++) acc[j] = fmaf(c0, bf2f(u0[j]), acc[j]);
    }

    const float4* b4 = (const float4*)bias;
    float4 ba = b4[f * 2], bb = b4[f * 2 + 1];
    float bv[8] = {ba.x, ba.y, ba.z, ba.w, bb.x, bb.y, bb.z, bb.w};
    u16x8 o;
#pragma unroll
    for (int j = 0; j < 8; j++) {
        float r = acc[j] + bv[j];
        if (do_relu) r = fmaxf(r, 0.f);
        o[j] = f2bf(r);
    }
    *((u16x8*)out + (size_t)node * 16 + f) = o;
}

// ---------------------------------------------------------------------------
// final aggregation, 40 bf16 features -> fp32 out.
// Block 320: 16 nodes, 20 lanes/node, 2 features (u16x2 = 4B) per lane.
// ---------------------------------------------------------------------------
__global__ __launch_bounds__(320) void agg40_bf16(const u16* __restrict__ g3,
                                                  const float* __restrict__ dinv,
                                                  const int* __restrict__ row_start,
                                                  const int* __restrict__ csr_src,
                                                  const float* __restrict__ bias,
                                                  float* __restrict__ out, int n) {
    int t = threadIdx.x;
    int node = blockIdx.x * 16 + t / 20;
    int fq = t % 20;                    // features 2fq, 2fq+1
    if (node >= n) return;
    float di = dinv[node];
    float s2 = di * di;
    u16x2 v = *(const u16x2*)(g3 + (size_t)node * 40 + fq * 2);
    float a0 = bf2f(v[0]) * s2;
    float a1 = bf2f(v[1]) * s2;

    int e0 = row_start[node], e1 = row_start[node + 1];
    int e = e0;
    for (; e + 3 < e1; e += 4) {
        int s0v = csr_src[e], s1v = csr_src[e + 1], s2v = csr_src[e + 2], s3v = csr_src[e + 3];
        float c0 = dinv[s0v] * di, c1 = dinv[s1v] * di;
        float c2 = dinv[s2v] * di, c3 = dinv[s3v] * di;
        u16x2 u0 = *(const u16x2*)(g3 + (size_t)s0v * 40 + fq * 2);
        u16x2 u1 = *(const u16x2*)(g3 + (size_t)s1v * 40 + fq * 2);
        u16x2 u2 = *(const u16x2*)(g3 + (size_t)s2v * 40 + fq * 2);
        u16x2 u3 = *(const u16x2*)(g3 + (size_t)s3v * 40 + fq * 2);
        a0 = fmaf(c0, bf2f(u0[0]), a0); a1 = fmaf(c0, bf2f(u0[1]), a1);
        a0 = fmaf(c1, bf2f(u1[0]), a0); a1 = fmaf(c1, bf2f(u1[1]), a1);
        a0 = fmaf(c2, bf2f(u2[0]), a0); a1 = fmaf(c2, bf2f(u2[1]), a1);
        a0 = fmaf(c3, bf2f(u3[0]), a0); a1 = fmaf(c3, bf2f(u3[1]), a1);
    }
    for (; e < e1; e++) {
        int sv = csr_src[e];
        float c0 = dinv[sv] * di;
        u16x2 u0 = *(const u16x2*)(g3 + (size_t)sv * 40 + fq * 2);
        a0 = fmaf(c0, bf2f(u0[0]), a0); a1 = fmaf(c0, bf2f(u0[1]), a1);
    }

    float2 b2v = *(const float2*)(bias + fq * 2);
    float2 o = make_float2(a0 + b2v.x, a1 + b2v.y);
    *(float2*)(out + (size_t)node * 40 + fq * 2) = o;
}

extern "C" void kernel_launch(void* const* d_in, const int* in_sizes, int n_in,
                              void* d_out, int out_size, void* d_ws, size_t ws_size,
                              hipStream_t stream) {
    const float* x  = (const float*)d_in[0];
    const int*   ei = (const int*)d_in[1];
    const float* W1 = (const float*)d_in[2];
    const float* b1 = (const float*)d_in[3];
    const float* W2 = (const float*)d_in[4];
    const float* b2 = (const float*)d_in[5];
    const float* W3 = (const float*)d_in[6];
    const float* b3 = (const float*)d_in[7];
    float* out = (float*)d_out;

    const int n = in_sizes[0] / 128;   // 170000
    const int E = in_sizes[1] / 2;     // 1200000
    const int nb = (n + 511) >> 9;     // 512-node buckets (<= 512 buckets)

    // workspace carve (256B aligned)
    char* p = (char*)d_ws;
    auto alloc = [&](size_t bytes) { void* r = (void*)p; p += (bytes + 255) & ~(size_t)255; return r; };
    int*   row_start = (int*)alloc((size_t)(n + 1) * 4);
    float* dinv      = (float*)alloc((size_t)n * 4);
    int*   csr_src   = (int*)alloc((size_t)E * 4);
    int2*  ebuf      = (int2*)alloc((size_t)E * 8);
    int*   bhist     = (int*)alloc(512 * 4);
    int*   bstart    = (int*)alloc(520 * 4);
    int*   bcur      = (int*)alloc(512 * 4);
    u16*   bufG      = (u16*)alloc((size_t)n * 128 * 2);   // gemm outputs (bf16)
    u16*   bufH      = (u16*)alloc((size_t)n * 128 * 2);   // agg outputs (bf16)
    u16*   g3b       = (u16*)alloc((size_t)n * 40 * 2);    // layer-3 gemm out (bf16)
    u16*   wt1       = (u16*)alloc(16384 * 2);
    u16*   wt2       = (u16*)alloc(16384 * 2);
    u16*   wt3       = (u16*)alloc(8192 * 2);              // [64][128], cols 40+ zero

    // --- weight convert (one launch: W1, W2, W3pad) ---
    wconv_all<<<160, 256, 0, stream>>>(W1, W2, W3, wt1, wt2, wt3);

    // --- bucketed CSR build ---
    hipMemsetAsync(bhist, 0, 512 * 4, stream);
    const int ebk = (E + 4095) / 4096;
    histA_kernel<<<ebk, 256, 0, stream>>>(ei, E, bhist);
    scanA_kernel<<<1, 256, 0, stream>>>(bhist, bstart, bcur, nb);
    bucket_scatter<<<ebk, 256, 0, stream>>>(ei, E, bcur, ebuf);
    fine_fill<<<nb, 256, 0, stream>>>(ebuf, bstart, row_start, dinv, csr_src, n, nb, E);

    const int gblk = (n + 127) / 128;

    // --- layer 1 (A fp32) ---
    gemm128_mfma<false><<<gblk, 256, 0, stream>>>(x, wt1, bufG, n);
    agg128_bf16<<<(n + 15) / 16, 256, 0, stream>>>(bufG, dinv, row_start, csr_src, b1, bufH, n, 1);
    // --- layer 2 (A bf16) ---
    gemm128_mfma<true><<<gblk, 256, 0, stream>>>(bufH, wt2, bufG, n);
    agg128_bf16<<<(n + 15) / 16, 256, 0, stream>>>(bufG, dinv, row_start, csr_src, b2, bufH, n, 1);
    // --- layer 3 (W first: A(hW3) == (Ah)W3, aggregate only 40 features) ---
    gemm40_mfma<<<gblk, 256, 0, stream>>>(bufH, wt3, g3b, n);
    agg40_bf16<<<(n + 15) / 16, 320, 0, stream>>>(g3b, dinv, row_start, csr_src, b3, out, n);
}

// Round 9
// 384.054 us; speedup vs baseline: 1.2725x; 1.0900x over previous
//
#include <hip/hip_runtime.h>

typedef unsigned short u16;
typedef u16   u16x8  __attribute__((ext_vector_type(8)));
typedef u16   u16x4  __attribute__((ext_vector_type(4)));
typedef u16   u16x2  __attribute__((ext_vector_type(2)));
typedef short short8v __attribute__((ext_vector_type(8)));
typedef float f32x16  __attribute__((ext_vector_type(16)));
typedef float f32x4   __attribute__((ext_vector_type(4)));

__device__ __forceinline__ u16 f2bf(float f) {
    unsigned u = __float_as_uint(f);
    unsigned r = (u + 0x7fffu + ((u >> 16) & 1u)) >> 16;   // round-to-nearest-even
    return (u16)r;
}
__device__ __forceinline__ float bf2f(u16 h) {
    return __uint_as_float(((unsigned)h) << 16);
}

// ---------------------------------------------------------------------------
// Bucketed CSR build (as R8): histA -> scanA -> bucket_scatter -> fine_fill
// ---------------------------------------------------------------------------
__global__ __launch_bounds__(256) void histA_kernel(const int* __restrict__ ei, int E,
                                                    int* __restrict__ bhist) {
    __shared__ int h[512];
    int t = threadIdx.x;
    h[t] = 0; h[t + 256] = 0;
    __syncthreads();
    int base = blockIdx.x * 4096 + t;
#pragma unroll
    for (int j = 0; j < 16; j++) {
        int e = base + j * 256;
        if (e < E) {
            int d = __builtin_nontemporal_load(ei + E + e);
            atomicAdd(&h[d >> 9], 1);
        }
    }
    __syncthreads();
    if (h[t])       atomicAdd(&bhist[t], h[t]);
    if (h[t + 256]) atomicAdd(&bhist[t + 256], h[t + 256]);
}

__global__ __launch_bounds__(256) void scanA_kernel(const int* __restrict__ bhist,
                                                    int* __restrict__ bstart,
                                                    int* __restrict__ bcur, int nb) {
    __shared__ int hh[512];
    __shared__ int ps[256];
    int t = threadIdx.x;
    hh[t]       = (t < nb) ? bhist[t] : 0;
    hh[t + 256] = (t + 256 < nb) ? bhist[t + 256] : 0;
    __syncthreads();
    int a0 = hh[2 * t], a1 = hh[2 * t + 1];
    int s = a0 + a1;
    ps[t] = s;
    __syncthreads();
    for (int off = 1; off < 256; off <<= 1) {
        int add = (t >= off) ? ps[t - off] : 0;
        __syncthreads();
        ps[t] += add;
        __syncthreads();
    }
    int ex = ps[t] - s;
    bstart[2 * t] = ex;         bcur[2 * t] = ex;
    bstart[2 * t + 1] = ex + a0; bcur[2 * t + 1] = ex + a0;
    if (t == 255) bstart[512] = ps[255];
}

__global__ __launch_bounds__(256) void bucket_scatter(const int* __restrict__ ei, int E,
                                                      int* __restrict__ bcur,
                                                      int2* __restrict__ ebuf) {
    __shared__ int h[512];
    __shared__ int gb[512];
    int t = threadIdx.x;
    h[t] = 0; h[t + 256] = 0;
    __syncthreads();
    int base = blockIdx.x * 4096 + t;
    int ss[16], dd[16], lr[16];
#pragma unroll
    for (int j = 0; j < 16; j++) {
        int e = base + j * 256;
        if (e < E) {
            ss[j] = __builtin_nontemporal_load(ei + e);
            dd[j] = __builtin_nontemporal_load(ei + E + e);
            lr[j] = atomicAdd(&h[dd[j] >> 9], 1);
        } else {
            dd[j] = -1;
        }
    }
    __syncthreads();
    if (h[t])       gb[t] = atomicAdd(&bcur[t], h[t]);
    if (h[t + 256]) gb[t + 256] = atomicAdd(&bcur[t + 256], h[t + 256]);
    __syncthreads();
#pragma unroll
    for (int j = 0; j < 16; j++) {
        if (dd[j] >= 0) {
            int b = dd[j] >> 9;
            ebuf[gb[b] + lr[j]] = make_int2(ss[j], dd[j]);
        }
    }
}

__global__ __launch_bounds__(256) void fine_fill(const int2* __restrict__ ebuf,
                                                 const int* __restrict__ bstart,
                                                 int* __restrict__ row_start,
                                                 float* __restrict__ dinv,
                                                 int* __restrict__ csr_src,
                                                 int n, int nb, int E) {
    __shared__ int h[512];
    __shared__ int cur[512];
    __shared__ int ps[256];
    int b = blockIdx.x;
    int t = threadIdx.x;
    int base = b << 9;
    int range = n - base; if (range > 512) range = 512;
    int bs = bstart[b], be = bstart[b + 1];

    h[t] = 0; h[t + 256] = 0;
    __syncthreads();
    for (int i = bs + t; i < be; i += 256) {
        int2 e = ebuf[i];
        atomicAdd(&h[e.y - base], 1);
    }
    __syncthreads();
    if (t < range)       dinv[base + t] = rsqrtf((float)(h[t] + 1));
    if (t + 256 < range) dinv[base + t + 256] = rsqrtf((float)(h[t + 256] + 1));
    int a0 = h[2 * t], a1 = h[2 * t + 1];
    int s = a0 + a1;
    ps[t] = s;
    __syncthreads();
    for (int off = 1; off < 256; off <<= 1) {
        int add = (t >= off) ? ps[t - off] : 0;
        __syncthreads();
        ps[t] += add;
        __syncthreads();
    }
    int ex = ps[t] - s;
    cur[2 * t] = ex;
    cur[2 * t + 1] = ex + a0;
    if (2 * t < range)     row_start[base + 2 * t] = bs + ex;
    if (2 * t + 1 < range) row_start[base + 2 * t + 1] = bs + ex + a0;
    if (b == nb - 1 && t == 0) row_start[n] = E;
    __syncthreads();
    for (int i = bs + t; i < be; i += 256) {
        int2 e = ebuf[i];
        int lp = atomicAdd(&cur[e.y - base], 1);
        csr_src[bs + lp] = e.x;
    }
}

// ---------------------------------------------------------------------------
// All weights -> bf16 [col][k] transposed, one launch.
// ---------------------------------------------------------------------------
__global__ void wconv_all(const float* __restrict__ W1, const float* __restrict__ W2,
                          const float* __restrict__ W3,
                          u16* __restrict__ WT1, u16* __restrict__ WT2,
                          u16* __restrict__ WT3) {
    int i = blockIdx.x * 256 + threadIdx.x;   // 0..40959
    if (i < 32768) {
        const float* W = (i < 16384) ? W1 : W2;
        u16* WT = (i < 16384) ? WT1 : WT2;
        int j = i & 16383;
        int k = j >> 7, col = j & 127;
        WT[col * 128 + k] = f2bf(W[j]);
    } else {
        int j = i - 32768;                    // 0..8191
        int col = j >> 7, k = j & 127;        // col 0..63
        WT3[j] = (col < 40) ? f2bf(W3[k * 40 + col]) : (u16)0;
    }
}

// ---------------------------------------------------------------------------
// out[n x 128](bf16) = A[n x 128] @ W[128 x 128] via bf16 MFMA, fp32 accum.
// 64-row tiles: As 16KB + Bs 32KB = 48KB LDS -> 3 blocks/CU.
// Waves 2x2: wr=(w>>1)*32 rows, wc=(w&1)*64 cols; 2 acc tiles/wave.
// ---------------------------------------------------------------------------
template <bool ABF>
__global__ __launch_bounds__(256) void gemm128_mfma(const void* __restrict__ Ap,
                                                    const u16* __restrict__ WT,
                                                    u16* __restrict__ out, int n) {
    __shared__ u16 As[64 * 128];
    __shared__ u16 Bs[128 * 128];
    const int t = threadIdx.x;
    const int r0 = blockIdx.x * 64;

#pragma unroll
    for (int j = 0; j < 8; j++) {
        int f = t + j * 256;
        int col = f >> 4;
        int k0 = (f & 15) * 8;
        u16x8 v = *(const u16x8*)(WT + col * 128 + k0);
        *(u16x8*)&Bs[col * 128 + (k0 ^ ((col & 7) << 3))] = v;
    }
    if (ABF) {
        const u16* A = (const u16*)Ap;
#pragma unroll
        for (int j = 0; j < 4; j++) {
            int f = t + j * 256;            // 1024 u16x8 chunks
            int row = f >> 4;
            int k0 = (f & 15) * 8;
            u16x8 v = {0, 0, 0, 0, 0, 0, 0, 0};
            if (r0 + row < n) v = *(const u16x8*)(A + (size_t)(r0 + row) * 128 + k0);
            *(u16x8*)&As[row * 128 + (k0 ^ ((row & 7) << 3))] = v;
        }
    } else {
        const float* A = (const float*)Ap;
#pragma unroll
        for (int j = 0; j < 8; j++) {
            int f = t + j * 256;            // 2048 float4 chunks
            int row = f >> 5;
            int k0 = (f & 31) * 4;
            float4 v = make_float4(0.f, 0.f, 0.f, 0.f);
            if (r0 + row < n) v = *(const float4*)(A + (size_t)(r0 + row) * 128 + k0);
            u16x4 b;
            b[0] = f2bf(v.x); b[1] = f2bf(v.y); b[2] = f2bf(v.z); b[3] = f2bf(v.w);
            *(u16x4*)&As[row * 128 + (k0 ^ ((row & 7) << 3))] = b;
        }
    }
    __syncthreads();

    const int w = t >> 6, lane = t & 63;
    const int wr = (w >> 1) * 32;
    const int wc = (w & 1) * 64;
    const int lr = lane & 31;
    const int kj = (lane >> 5) * 8;
    const int swz = (lr & 7) << 3;

    f32x16 acc0, acc1;
#pragma unroll
    for (int i = 0; i < 16; i++) { acc0[i] = 0.f; acc1[i] = 0.f; }

#pragma unroll
    for (int ks = 0; ks < 8; ks++) {
        int ko = (ks * 16 + kj) ^ swz;
        short8v a  = *(const short8v*)&As[(wr + lr) * 128 + ko];
        short8v b0 = *(const short8v*)&Bs[(wc + lr) * 128 + ko];
        short8v b1 = *(const short8v*)&Bs[(wc + 32 + lr) * 128 + ko];
        acc0 = __builtin_amdgcn_mfma_f32_32x32x16_bf16(a, b0, acc0, 0, 0, 0);
        acc1 = __builtin_amdgcn_mfma_f32_32x32x16_bf16(a, b1, acc1, 0, 0, 0);
    }

    const int rb = (lane >> 5) * 4;
#pragma unroll
    for (int r = 0; r < 16; r++) {
        int rr = (r & 3) + 8 * (r >> 2) + rb;
        int row = r0 + wr + rr;
        if (row < n) {
            out[(size_t)row * 128 + wc + lr]      = f2bf(acc0[r]);
            out[(size_t)row * 128 + wc + 32 + lr] = f2bf(acc1[r]);
        }
    }
}

// ---------------------------------------------------------------------------
// pull aggregation, 128 bf16 features: 16 nodes / 256-thr block,
// 16 lanes/node x 8 bf16 (16B loads), 4/2/1 unroll ladder.
// FUSE=1 (layer 2): instead of writing the row to global, park it in LDS and
// fuse the n x 128 @ 128 x 40 GEMM (W3) via 16x16x32 MFMA -> writes g3 only.
// ---------------------------------------------------------------------------
template <int FUSE>
__global__ __launch_bounds__(256) void agg128_k(const u16* __restrict__ hw,
                                                const float* __restrict__ dinv,
                                                const int* __restrict__ row_start,
                                                const int* __restrict__ csr_src,
                                                const float* __restrict__ bias,
                                                u16* __restrict__ out,
                                                const u16* __restrict__ wt3,
                                                u16* __restrict__ g3, int n) {
    __shared__ u16 wlds[FUSE ? 48 * 136 : 1];   // [col][k] padded (+8 u16)
    __shared__ u16 rows[FUSE ? 16 * 136 : 1];   // [node][k] padded

    int t = threadIdx.x;
    if (FUSE) {
        // stage wt3 cols 0..47 (cols 40+ are zero in wt3): 768 u16x8 chunks
#pragma unroll
        for (int j = 0; j < 3; j++) {
            int f = t + j * 256;
            int c = f >> 4;
            int k0 = (f & 15) * 8;
            *(u16x8*)&wlds[c * 136 + k0] = *(const u16x8*)(wt3 + c * 128 + k0);
        }
    }

    int node = blockIdx.x * 16 + (t >> 4);
    int f = t & 15;
    bool alive = node < n;
    u16x8 o = {0, 0, 0, 0, 0, 0, 0, 0};
    if (alive) {
        const u16x8* hw8 = (const u16x8*)hw;
        float di = dinv[node];
        float s2 = di * di;
        u16x8 v = hw8[(size_t)node * 16 + f];
        float acc[8];
#pragma unroll
        for (int j = 0; j < 8; j++) acc[j] = bf2f(v[j]) * s2;

        int e0 = row_start[node], e1 = row_start[node + 1];
        int e = e0;
        for (; e + 3 < e1; e += 4) {
            int s0v = csr_src[e], s1v = csr_src[e + 1], s2v = csr_src[e + 2], s3v = csr_src[e + 3];
            float c0 = dinv[s0v] * di, c1 = dinv[s1v] * di;
            float c2 = dinv[s2v] * di, c3 = dinv[s3v] * di;
            u16x8 u0 = hw8[(size_t)s0v * 16 + f];
            u16x8 u1 = hw8[(size_t)s1v * 16 + f];
            u16x8 u2 = hw8[(size_t)s2v * 16 + f];
            u16x8 u3 = hw8[(size_t)s3v * 16 + f];
#pragma unroll
            for (int j = 0; j < 8; j++) acc[j] = fmaf(c0, bf2f(u0[j]), acc[j]);
#pragma unroll
            for (int j = 0; j < 8; j++) acc[j] = fmaf(c1, bf2f(u1[j]), acc[j]);
#pragma unroll
            for (int j = 0; j < 8; j++) acc[j] = fmaf(c2, bf2f(u2[j]), acc[j]);
#pragma unroll
            for (int j = 0; j < 8; j++) acc[j] = fmaf(c3, bf2f(u3[j]), acc[j]);
        }
        if (e + 1 < e1) {
            int s0v = csr_src[e], s1v = csr_src[e + 1];
            float c0 = dinv[s0v] * di, c1 = dinv[s1v] * di;
            u16x8 u0 = hw8[(size_t)s0v * 16 + f];
            u16x8 u1 = hw8[(size_t)s1v * 16 + f];
#pragma unroll
            for (int j = 0; j < 8; j++) acc[j] = fmaf(c0, bf2f(u0[j]), acc[j]);
#pragma unroll
            for (int j = 0; j < 8; j++) acc[j] = fmaf(c1, bf2f(u1[j]), acc[j]);
            e += 2;
        }
        if (e < e1) {
            int sv = csr_src[e];
            float c0 = dinv[sv] * di;
            u16x8 u0 = hw8[(size_t)sv * 16 + f];
#pragma unroll
            for (int j = 0; j < 8; j++) acc[j] = fmaf(c0, bf2f(u0[j]), acc[j]);
        }

        const float4* b4 = (const float4*)bias;
        float4 ba = b4[f * 2], bb = b4[f * 2 + 1];
        float bv[8] = {ba.x, ba.y, ba.z, ba.w, bb.x, bb.y, bb.z, bb.w};
#pragma unroll
        for (int j = 0; j < 8; j++) {
            float r = fmaxf(acc[j] + bv[j], 0.f);   // relu on both layers
            o[j] = f2bf(r);
        }
        if (!FUSE) *((u16x8*)out + (size_t)node * 16 + f) = o;
    }

    if (FUSE) {
        if (alive) *(u16x8*)&rows[(t >> 4) * 136 + f * 8] = o;
        __syncthreads();
        // mini-GEMM: D[16 nodes][48 cols] = rows[16][128] @ W3[128][48]
        // wave w<3 handles col tile w*16; 4 K-steps of mfma_f32_16x16x32_bf16
        int w = t >> 6, lane = t & 63;
        if (w < 3) {
            int cr = lane & 15;       // A row / B col within tile
            int kg = lane >> 4;       // k-group (8 elems each)
            f32x4 acc4 = {0.f, 0.f, 0.f, 0.f};
#pragma unroll
            for (int ks = 0; ks < 4; ks++) {
                int kk = ks * 32 + kg * 8;
                short8v a = *(const short8v*)&rows[cr * 136 + kk];
                short8v b = *(const short8v*)&wlds[(w * 16 + cr) * 136 + kk];
                acc4 = __builtin_amdgcn_mfma_f32_16x16x32_bf16(a, b, acc4, 0, 0, 0);
            }
            // D: col = lane&15, row = (lane>>4)*4 + r
            int col = w * 16 + (lane & 15);
            if (col < 40) {
#pragma unroll
                for (int r = 0; r < 4; r++) {
                    int nd = blockIdx.x * 16 + kg * 4 + r;
                    if (nd < n) g3[(size_t)nd * 40 + col] = f2bf(acc4[r]);
                }
            }
        }
    }
}

// ---------------------------------------------------------------------------
// final aggregation, 40 bf16 features -> fp32 out.
// Block 320: 16 nodes, 20 lanes/node, 2 features (u16x2 = 4B) per lane.
// ---------------------------------------------------------------------------
__global__ __launch_bounds__(320) void agg40_bf16(const u16* __restrict__ g3,
                                                  const float* __restrict__ dinv,
                                                  const int* __restrict__ row_start,
                                                  const int* __restrict__ csr_src,
                                                  const float* __restrict__ bias,
                                                  float* __restrict__ out, int n) {
    int t = threadIdx.x;
    int node = blockIdx.x * 16 + t / 20;
    int fq = t % 20;                    // features 2fq, 2fq+1
    if (node >= n) return;
    float di = dinv[node];
    float s2 = di * di;
    u16x2 v = *(const u16x2*)(g3 + (size_t)node * 40 + fq * 2);
    float a0 = bf2f(v[0]) * s2;
    float a1 = bf2f(v[1]) * s2;

    int e0 = row_start[node], e1 = row_start[node + 1];
    int e = e0;
    for (; e + 3 < e1; e += 4) {
        int s0v = csr_src[e], s1v = csr_src[e + 1], s2v = csr_src[e + 2], s3v = csr_src[e + 3];
        float c0 = dinv[s0v] * di, c1 = dinv[s1v] * di;
        float c2 = dinv[s2v] * di, c3 = dinv[s3v] * di;
        u16x2 u0 = *(const u16x2*)(g3 + (size_t)s0v * 40 + fq * 2);
        u16x2 u1 = *(const u16x2*)(g3 + (size_t)s1v * 40 + fq * 2);
        u16x2 u2 = *(const u16x2*)(g3 + (size_t)s2v * 40 + fq * 2);
        u16x2 u3 = *(const u16x2*)(g3 + (size_t)s3v * 40 + fq * 2);
        a0 = fmaf(c0, bf2f(u0[0]), a0); a1 = fmaf(c0, bf2f(u0[1]), a1);
        a0 = fmaf(c1, bf2f(u1[0]), a0); a1 = fmaf(c1, bf2f(u1[1]), a1);
        a0 = fmaf(c2, bf2f(u2[0]), a0); a1 = fmaf(c2, bf2f(u2[1]), a1);
        a0 = fmaf(c3, bf2f(u3[0]), a0); a1 = fmaf(c3, bf2f(u3[1]), a1);
    }
    if (e + 1 < e1) {
        int s0v = csr_src[e], s1v = csr_src[e + 1];
        float c0 = dinv[s0v] * di, c1 = dinv[s1v] * di;
        u16x2 u0 = *(const u16x2*)(g3 + (size_t)s0v * 40 + fq * 2);
        u16x2 u1 = *(const u16x2*)(g3 + (size_t)s1v * 40 + fq * 2);
        a0 = fmaf(c0, bf2f(u0[0]), a0); a1 = fmaf(c0, bf2f(u0[1]), a1);
        a0 = fmaf(c1, bf2f(u1[0]), a0); a1 = fmaf(c1, bf2f(u1[1]), a1);
        e += 2;
    }
    if (e < e1) {
        int sv = csr_src[e];
        float c0 = dinv[sv] * di;
        u16x2 u0 = *(const u16x2*)(g3 + (size_t)sv * 40 + fq * 2);
        a0 = fmaf(c0, bf2f(u0[0]), a0); a1 = fmaf(c0, bf2f(u0[1]), a1);
    }

    float2 b2v = *(const float2*)(bias + fq * 2);
    float2 o = make_float2(a0 + b2v.x, a1 + b2v.y);
    *(float2*)(out + (size_t)node * 40 + fq * 2) = o;
}

extern "C" void kernel_launch(void* const* d_in, const int* in_sizes, int n_in,
                              void* d_out, int out_size, void* d_ws, size_t ws_size,
                              hipStream_t stream) {
    const float* x  = (const float*)d_in[0];
    const int*   ei = (const int*)d_in[1];
    const float* W1 = (const float*)d_in[2];
    const float* b1 = (const float*)d_in[3];
    const float* W2 = (const float*)d_in[4];
    const float* b2 = (const float*)d_in[5];
    const float* W3 = (const float*)d_in[6];
    const float* b3 = (const float*)d_in[7];
    float* out = (float*)d_out;

    const int n = in_sizes[0] / 128;   // 170000
    const int E = in_sizes[1] / 2;     // 1200000
    const int nb = (n + 511) >> 9;     // 512-node buckets

    // workspace carve (256B aligned)
    char* p = (char*)d_ws;
    auto alloc = [&](size_t bytes) { void* r = (void*)p; p += (bytes + 255) & ~(size_t)255; return r; };
    int*   row_start = (int*)alloc((size_t)(n + 1) * 4);
    float* dinv      = (float*)alloc((size_t)n * 4);
    int*   csr_src   = (int*)alloc((size_t)E * 4);
    int2*  ebuf      = (int2*)alloc((size_t)E * 8);
    int*   bhist     = (int*)alloc(512 * 4);
    int*   bstart    = (int*)alloc(520 * 4);
    int*   bcur      = (int*)alloc(512 * 4);
    u16*   bufG      = (u16*)alloc((size_t)n * 128 * 2);   // gemm outputs (bf16)
    u16*   bufH      = (u16*)alloc((size_t)n * 128 * 2);   // layer-1 agg out (bf16)
    u16*   g3b       = (u16*)alloc((size_t)n * 40 * 2);    // fused layer-3 gemm out
    u16*   wt1       = (u16*)alloc(16384 * 2);
    u16*   wt2       = (u16*)alloc(16384 * 2);
    u16*   wt3       = (u16*)alloc(8192 * 2);              // [64][128], cols 40+ zero

    // --- weight convert ---
    wconv_all<<<160, 256, 0, stream>>>(W1, W2, W3, wt1, wt2, wt3);

    // --- bucketed CSR build ---
    hipMemsetAsync(bhist, 0, 512 * 4, stream);
    const int ebk = (E + 4095) / 4096;
    histA_kernel<<<ebk, 256, 0, stream>>>(ei, E, bhist);
    scanA_kernel<<<1, 256, 0, stream>>>(bhist, bstart, bcur, nb);
    bucket_scatter<<<ebk, 256, 0, stream>>>(ei, E, bcur, ebuf);
    fine_fill<<<nb, 256, 0, stream>>>(ebuf, bstart, row_start, dinv, csr_src, n, nb, E);

    const int gblk = (n + 63) / 64;
    const int ablk = (n + 15) / 16;

    // --- layer 1 (A fp32) ---
    gemm128_mfma<false><<<gblk, 256, 0, stream>>>(x, wt1, bufG, n);
    agg128_k<0><<<ablk, 256, 0, stream>>>(bufG, dinv, row_start, csr_src, b1, bufH, nullptr, nullptr, n);
    // --- layer 2 (A bf16) + fused layer-3 GEMM (rows @ W3 -> g3b) ---
    gemm128_mfma<true><<<gblk, 256, 0, stream>>>(bufH, wt2, bufG, n);
    agg128_k<1><<<ablk, 256, 0, stream>>>(bufG, dinv, row_start, csr_src, b2, nullptr, wt3, g3b, n);
    // --- final aggregation over 40 features ---
    agg40_bf16<<<ablk, 320, 0, stream>>>(g3b, dinv, row_start, csr_src, b3, out, n);
}